// Round 1
// 121.427 us; speedup vs baseline: 1.0287x; 1.0287x over previous
//
#include <hip/hip_runtime.h>

#define THREADS 256
#define WAVE 64
#define GROUPS_PER_BLOCK (THREADS * 2)   // 2 groups of 4 samples per thread

// Stage 1: each thread handles 8 samples as two independent groups of 4.
// All vector loads for both groups are issued before any compute (12 loads
// in flight per thread). The four loss channels are linear in the final
// weighted sum, so weights are applied per-thread and a SINGLE scalar is
// wave-reduced (6 shuffles) -> one float partial per block.
__global__ __launch_bounds__(THREADS) void loss_reduce(
    const float4* __restrict__ pred4,   // 2 float4 per group of 4 samples
    const float4* __restrict__ tgt4,
    const float4* __restrict__ prev4,
    const int4*   __restrict__ dt4,
    const int4*   __restrict__ pv4,
    float* __restrict__ partials,
    int n4)
{
    int i0 = blockIdx.x * GROUPS_PER_BLOCK + threadIdx.x;
    int i1 = i0 + THREADS;
    bool v0 = (i0 < n4);
    bool v1 = (i1 < n4);

    float4 a0, a1, t0, q0;  int4 d0, e0;
    float4 b0, b1, t1, q1;  int4 d1, e1;

    if (v0) {
        a0 = pred4[2 * i0];
        a1 = pred4[2 * i0 + 1];
        t0 = tgt4[i0];
        q0 = prev4[i0];
        d0 = dt4[i0];
        e0 = pv4[i0];
    }
    if (v1) {
        b0 = pred4[2 * i1];
        b1 = pred4[2 * i1 + 1];
        t1 = tgt4[i1];
        q1 = prev4[i1];
        d1 = dt4[i1];
        e1 = pv4[i1];
    }

    float s0 = 0.f, s1 = 0.f, s2 = 0.f, s3 = 0.f;

    if (v0) {
        float lo[4]  = {a0.x, a0.z, a1.x, a1.z};
        float up[4]  = {a0.y, a0.w, a1.y, a1.w};
        float tga[4] = {t0.x, t0.y, t0.z, t0.w};
        float ppa[4] = {q0.x, q0.y, q0.z, q0.w};
        int   dta[4] = {d0.x, d0.y, d0.z, d0.w};
        int   pva[4] = {e0.x, e0.y, e0.z, e0.w};
#pragma unroll
        for (int j = 0; j < 4; ++j) {
            float c = 0.5f * (lo[j] + up[j]);
            float d = tga[j] - c;
            s0 += d * d;
            s1 += up[j] - lo[j];
            s2 += fmaxf(lo[j] - up[j], 0.0f);
            float diff = c - ppa[j];
            float pen = (pva[j] == 0) ? fmaxf(diff, 0.0f) : fmaxf(-diff, 0.0f);
            s3 += (dta[j] != 0) ? pen : 0.0f;
        }
    }
    if (v1) {
        float lo[4]  = {b0.x, b0.z, b1.x, b1.z};
        float up[4]  = {b0.y, b0.w, b1.y, b1.w};
        float tga[4] = {t1.x, t1.y, t1.z, t1.w};
        float ppa[4] = {q1.x, q1.y, q1.z, q1.w};
        int   dta[4] = {d1.x, d1.y, d1.z, d1.w};
        int   pva[4] = {e1.x, e1.y, e1.z, e1.w};
#pragma unroll
        for (int j = 0; j < 4; ++j) {
            float c = 0.5f * (lo[j] + up[j]);
            float d = tga[j] - c;
            s0 += d * d;
            s1 += up[j] - lo[j];
            s2 += fmaxf(lo[j] - up[j], 0.0f);
            float diff = c - ppa[j];
            float pen = (pva[j] == 0) ? fmaxf(diff, 0.0f) : fmaxf(-diff, 0.0f);
            s3 += (dta[j] != 0) ? pen : 0.0f;
        }
    }

    // Weights are linear -> fold into one scalar before reduction.
    float w = 1.5f * s0 + 0.1f * s1 + 10.0f * s2 + 0.5f * s3;

#pragma unroll
    for (int off = 32; off > 0; off >>= 1)
        w += __shfl_down(w, off, WAVE);

    __shared__ float smem[THREADS / WAVE];
    if ((threadIdx.x & 63) == 0) smem[threadIdx.x >> 6] = w;
    __syncthreads();
    if (threadIdx.x == 0) {
        float acc = smem[0];
#pragma unroll
        for (int wv = 1; wv < THREADS / WAVE; ++wv) acc += smem[wv];
        partials[blockIdx.x] = acc;
    }
}

// Stage 2: single block combines per-block weighted partials (+ defensive
// scalar tail) and divides by n.
__global__ __launch_bounds__(THREADS) void loss_final(
    const float* __restrict__ partials, int nblocks,
    const float* __restrict__ pred, const float* __restrict__ tgt,
    const float* __restrict__ prev, const int* __restrict__ dt,
    const int* __restrict__ pvv,
    int tail_start, int n,
    float* __restrict__ out)
{
    float s = 0.f;
    for (int t = threadIdx.x; t < nblocks; t += THREADS)
        s += partials[t];

    if (threadIdx.x == 0) {
        for (int i = tail_start; i < n; ++i) {
            float lo = pred[2 * i], up = pred[2 * i + 1];
            float c = 0.5f * (lo + up);
            float d = tgt[i] - c;
            float pen = (pvv[i] == 0) ? fmaxf(c - prev[i], 0.f)
                                      : fmaxf(prev[i] - c, 0.f);
            s += 1.5f * d * d + 0.1f * (up - lo) + 10.0f * fmaxf(lo - up, 0.f)
               + 0.5f * ((dt[i] != 0) ? pen : 0.f);
        }
    }

#pragma unroll
    for (int off = 32; off > 0; off >>= 1)
        s += __shfl_down(s, off, WAVE);

    __shared__ float smem[THREADS / WAVE];
    if ((threadIdx.x & 63) == 0) smem[threadIdx.x >> 6] = s;
    __syncthreads();
    if (threadIdx.x == 0) {
        float acc = smem[0];
#pragma unroll
        for (int wv = 1; wv < THREADS / WAVE; ++wv) acc += smem[wv];
        out[0] = acc / (float)n;
    }
}

extern "C" void kernel_launch(void* const* d_in, const int* in_sizes, int n_in,
                              void* d_out, int out_size, void* d_ws, size_t ws_size,
                              hipStream_t stream) {
    const float* pred   = (const float*)d_in[0];
    const float* target = (const float*)d_in[1];
    const float* prev   = (const float*)d_in[2];
    const int*   dt     = (const int*)d_in[3];
    const int*   pv     = (const int*)d_in[4];
    float* out = (float*)d_out;

    int n  = in_sizes[3];          // B (delta_time is (B,))
    int n4 = n >> 2;               // groups of 4 samples
    int nblocks = (n4 + GROUPS_PER_BLOCK - 1) / GROUPS_PER_BLOCK;  // 2048

    float* partials = (float*)d_ws;   // 2048 * 4 B = 8 KB

    loss_reduce<<<nblocks, THREADS, 0, stream>>>(
        (const float4*)pred, (const float4*)target, (const float4*)prev,
        (const int4*)dt, (const int4*)pv, partials, n4);

    loss_final<<<1, THREADS, 0, stream>>>(
        partials, nblocks, pred, target, prev, dt, pv, n4 * 4, n, out);
}